// Round 5
// baseline (2622.740 us; speedup 1.0000x reference)
//
#include <hip/hip_runtime.h>
#include <hip/hip_bf16.h>
#include <stdint.h>

#define T_STEPS 512
#define BATCH   256
#define HID     256

#define NRWG   128     // recurrence WGs: 32 batch-groups x 4 gates
#define NWWG   128     // xgemm producer WGs
#define NWG    256
#define RING   4       // ring slots
#define CHUNK  8       // time steps per chunk
#define NCHUNK 64
#define TPC    64      // tiles per chunk: (8*256/128) * (1024/256)
#define SLOT_F (CHUNK*256*1024)   // floats per ring slot (8 MB)

using short8 = __attribute__((ext_vector_type(8))) short;
using f32x4  = __attribute__((ext_vector_type(4))) float;

#define VMCNT0() asm volatile("s_waitcnt vmcnt(0)" ::: "memory")

__device__ inline unsigned short f2bf(float f) {
  unsigned u = __float_as_uint(f);
  unsigned r = (u + 0x7fffu + ((u >> 16) & 1u)) >> 16;
  return (unsigned short)r;
}
__device__ inline float sigm(float x)   { return __builtin_amdgcn_rcpf(1.0f + __expf(-x)); }
__device__ inline float tanh_f(float x) { return 2.0f * __builtin_amdgcn_rcpf(1.0f + __expf(-2.0f * x)) - 1.0f; }

__device__ inline int ld_rlx(const int* p) {
  return __hip_atomic_load(p, __ATOMIC_RELAXED, __HIP_MEMORY_SCOPE_AGENT);
}
__device__ inline void add_rlx(int* p, int v) {
  __hip_atomic_fetch_add(p, v, __ATOMIC_RELAXED, __HIP_MEMORY_SCOPE_AGENT);
}
__device__ inline float ldg_coh(const float* p) {
  return __hip_atomic_load(p, __ATOMIC_RELAXED, __HIP_MEMORY_SCOPE_AGENT);
}
__device__ inline void stg_coh(float* p, float v) {
  __hip_atomic_store(p, v, __ATOMIC_RELAXED, __HIP_MEMORY_SCOPE_AGENT);
}
// 16B coherent (LLC) store/load, bypassing L1/L2 via sc0 sc1
__device__ inline void st16_coh(float* p, f32x4 v) {
  asm volatile("global_store_dwordx4 %0, %1, off sc0 sc1" :: "v"(p), "v"(v) : "memory");
}

// h LDS swizzle: frag-linear layout, XOR bits 4..5 with bits 8..9
__device__ inline int hswz(int byte) { return byte ^ (((byte >> 8) & 3) << 4); }

// ---------------- prep: pack weights + zero flags/packets ----------------
__global__ __launch_bounds__(256) void prep_kernel(
    const float* __restrict__ Wf, const float* __restrict__ Wi,
    const float* __restrict__ Wg, const float* __restrict__ Wo,
    const float* __restrict__ bf_, const float* __restrict__ bi_,
    const float* __restrict__ bg_, const float* __restrict__ bo_,
    const float* __restrict__ thf, const float* __restrict__ thi,
    const float* __restrict__ thg, const float* __restrict__ tho,
    unsigned short* __restrict__ Wfull, float* __restrict__ cvec,
    int* __restrict__ flags, float* __restrict__ pk)
{
  int j = blockIdx.x;            // 0..1023 output col
  int g = j >> 8, col = j & 255;
  const float* W  = (g==0)?Wf:(g==1)?Wi:(g==2)?Wg:Wo;
  const float* bb = (g==0)?bf_:(g==1)?bi_:(g==2)?bg_:bo_;
  const float* th = (g==0)?thf:(g==1)?thi:(g==2)?thg:tho;
  const float* wrow = W + (size_t)col * 768;
  for (int k = threadIdx.x; k < 768; k += blockDim.x)
    Wfull[(size_t)j * 768 + k] = f2bf(wrow[k]);
  if (threadIdx.x == 0) cvec[j] = bb[col] + th[col];
  if (j == 0) for (int i = threadIdx.x; i < 512; i += 256) flags[i] = 0;
  // zero the 4MB packet region (kills stale embedded seqs across replays)
  float* pz = pk + (size_t)j * 1024;
  for (int i = threadIdx.x; i < 1024; i += 256) pz[i] = 0.0f;
}

// ---------------- persistent kernel ----------------
__global__ __launch_bounds__(512, 2) void persist_kernel(
    const float* __restrict__ X,
    const unsigned short* __restrict__ Wfull,
    const float* __restrict__ cvec,
    float* __restrict__ ring,
    float* __restrict__ pk,       // [2][32][4][8][64][8] floats (packets)
    int* __restrict__ done,       // [64]
    int* __restrict__ consumed,   // [1]
    float* __restrict__ out)
{
  __shared__ union {
    struct { unsigned short hL[4096]; float z[8][1032]; int rdy[2]; } rec;
    struct { unsigned short aL[4096]; unsigned short bL[8192]; } gem;
  } sm;

  int bid = blockIdx.x, tid = threadIdx.x;
  int lane = tid & 63, wv = tid >> 6;       // 8 waves
  int l15 = lane & 15, lk = lane >> 4;

  if (bid < NRWG) {
    // ================= recurrence =================
    int bg = bid >> 2, g = bid & 3;

    for (int i = tid; i < 4096; i += 512) sm.rec.hL[i] = 0;
    if (tid == 0) { sm.rec.rdy[0] = 0; sm.rec.rdy[1] = 0; }

    // Wh fragments (wave wv covers gate cols wv*32..+31)
    short8 af[2][8];
#pragma unroll
    for (int ti = 0; ti < 2; ++ti)
#pragma unroll
      for (int kk = 0; kk < 8; ++kk)
        af[ti][kk] = *(const short8*)(Wfull +
            (size_t)(g*256 + wv*32 + ti*16 + l15)*768 + 512 + kk*32 + lk*8);

    float creg[4] = {0.f, 0.f, 0.f, 0.f};   // c-state: row=wv, col=s*64+lane
    float zx[4];
    bool pf_prev = false;
    __syncthreads();

    for (int t = 0; t < T_STEPS; ++t) {
      int cIdx = t >> 3;
      if ((t & 7) == 0 && !pf_prev) {
        if (tid == 0) { while (ld_rlx(&done[cIdx]) < TPC) __builtin_amdgcn_s_sleep(1); }
        __syncthreads();
        const float* zp = ring + (size_t)(cIdx & (RING-1))*SLOT_F
                        + ((size_t)(t & 7)*256 + bg*8 + wv)*1024 + g*256 + lane;
#pragma unroll
        for (int s = 0; s < 4; ++s) zx[s] = ldg_coh(zp + s*64);
      }

      // ---- MFMA: z_h = Wh_cols x h_rows (B-frags from frag-linear LDS) ----
      short8 bfr[8];
#pragma unroll
      for (int kk = 0; kk < 8; ++kk)
        bfr[kk] = *(const short8*)((const char*)sm.rec.hL + hswz(kk*1024 + lane*16));
      f32x4 acc0 = {0.f,0.f,0.f,0.f}, acc1 = {0.f,0.f,0.f,0.f};
#pragma unroll
      for (int kk = 0; kk < 8; ++kk) {
        acc0 = __builtin_amdgcn_mfma_f32_16x16x32_bf16(af[0][kk], bfr[kk], acc0, 0, 0, 0);
        acc1 = __builtin_amdgcn_mfma_f32_16x16x32_bf16(af[1][kk], bfr[kk], acc1, 0, 0, 0);
      }
      if (l15 < 8) {   // D: col(batch)=l15, row(Wh col)=lk*4+reg
        *(f32x4*)&sm.rec.z[l15][wv*32 +      lk*4] = acc0;
        *(f32x4*)&sm.rec.z[l15][wv*32 + 16 + lk*4] = acc1;
      }
      __syncthreads();

      // ---- scan + activation (wave wv = batch row) ----
      float v[4];
#pragma unroll
      for (int s = 0; s < 4; ++s)
        v[s] = __cosf(sm.rec.z[wv][s*64 + lane] + zx[s]);
#pragma unroll
      for (int off = 1; off < 64; off <<= 1) {
        float u0 = __shfl_up(v[0], (unsigned)off, 64);
        float u1 = __shfl_up(v[1], (unsigned)off, 64);
        float u2 = __shfl_up(v[2], (unsigned)off, 64);
        float u3 = __shfl_up(v[3], (unsigned)off, 64);
        if (lane >= off) { v[0]*=u0; v[1]*=u1; v[2]*=u2; v[3]*=u3; }
      }
      float t0 = __shfl(v[0], 63, 64), t1 = __shfl(v[1], 63, 64), t2 = __shfl(v[2], 63, 64);
      float p1 = t0, p2 = t0*t1, p3 = p2*t2;
      float a0 = v[0], a1 = v[1]*p1, a2 = v[2]*p2, a3 = v[3]*p3;
      float act[4];
      if (g == 2) { act[0]=tanh_f(a0); act[1]=tanh_f(a1); act[2]=tanh_f(a2); act[3]=tanh_f(a3); }
      else        { act[0]=sigm(a0);   act[1]=sigm(a1);   act[2]=sigm(a2);   act[3]=sigm(a3); }

      // ---- publish: two 16B packets with embedded seq (single-RT exchange)
      int par = t & 1, T1 = t + 1;
      float seqf = __int_as_float(T1);
      float* myb = pk + ((((size_t)par*32 + bg)*4 + g)*8 + wv)*512 + (size_t)lane*8;
      f32x4 P1 = {act[0], act[1], act[2], seqf};
      f32x4 P2 = {act[3], seqf, 0.f, 0.f};
      st16_coh(myb, P1);
      st16_coh(myb + 4, P2);

      // chunk-readiness speculation for t+1 (published for step t+1 via rdy[par^1])
      int rdyv = sm.rec.rdy[par];
      bool pf = (((t+1) & 7) == 0) && (t+1 < T_STEPS) && (rdyv >= TPC);
      if (tid == 0) {
        int cn = cIdx + 1;
        sm.rec.rdy[par ^ 1] = ld_rlx(&done[cn]);
      }
      // zx prefetch for t+1
      if (t+1 < T_STEPS && (((t+1) & 7) != 0 || pf)) {
        int cN = (t+1) >> 3;
        const float* zp = ring + (size_t)(cN & (RING-1))*SLOT_F
                        + ((size_t)((t+1) & 7)*256 + bg*8 + wv)*1024 + g*256 + lane;
#pragma unroll
        for (int s = 0; s < 4; ++s) zx[s] = ldg_coh(zp + s*64);
      }
      pf_prev = pf;

      // ---- poll the 3 peer gates' packets directly ----
      int q0 = (g+1)&3, q1 = (g+2)&3, q2 = (g+3)&3;
      const float* A1 = pk + ((((size_t)par*32 + bg)*4 + q0)*8 + wv)*512 + (size_t)lane*8;
      const float* B1 = pk + ((((size_t)par*32 + bg)*4 + q1)*8 + wv)*512 + (size_t)lane*8;
      const float* C1 = pk + ((((size_t)par*32 + bg)*4 + q2)*8 + wv)*512 + (size_t)lane*8;
      f32x4 qa1, qa2, qb1, qb2, qc1, qc2;
      while (true) {
        asm volatile(
          "global_load_dwordx4 %0, %6,  off sc0 sc1\n\t"
          "global_load_dwordx4 %1, %7,  off sc0 sc1\n\t"
          "global_load_dwordx4 %2, %8,  off sc0 sc1\n\t"
          "global_load_dwordx4 %3, %9,  off sc0 sc1\n\t"
          "global_load_dwordx4 %4, %10, off sc0 sc1\n\t"
          "global_load_dwordx4 %5, %11, off sc0 sc1\n\t"
          "s_waitcnt vmcnt(0)"
          : "=&v"(qa1), "=&v"(qa2), "=&v"(qb1), "=&v"(qb2), "=&v"(qc1), "=&v"(qc2)
          : "v"(A1), "v"(A1+4), "v"(B1), "v"(B1+4), "v"(C1), "v"(C1+4)
          : "memory");
        if (__float_as_int(qa1[3]) >= T1 && __float_as_int(qa2[1]) >= T1 &&
            __float_as_int(qb1[3]) >= T1 && __float_as_int(qb2[1]) >= T1 &&
            __float_as_int(qc1[3]) >= T1 && __float_as_int(qc2[1]) >= T1) break;
      }

      // gather acts by gate index: own gate g from registers
      float vals[4][4];
#pragma unroll
      for (int s = 0; s < 4; ++s) vals[g][s] = act[s];
      vals[q0][0]=qa1[0]; vals[q0][1]=qa1[1]; vals[q0][2]=qa1[2]; vals[q0][3]=qa2[0];
      vals[q1][0]=qb1[0]; vals[q1][1]=qb1[1]; vals[q1][2]=qb1[2]; vals[q1][3]=qb2[0];
      vals[q2][0]=qc1[0]; vals[q2][1]=qc1[1]; vals[q2][2]=qc1[2]; vals[q2][3]=qc2[0];

      int brow = bg*8 + wv;
#pragma unroll
      for (int s = 0; s < 4; ++s) {
        float cn = vals[0][s]*creg[s] + vals[1][s]*vals[2][s];
        creg[s] = cn;
        float h = vals[3][s]*tanh_f(cn);
        // h -> frag-linear LDS (element k = s*64+lane, row wv)
        int k = s*64 + lane;
        int byte = (k >> 5)*1024 + ((((k >> 3) & 3)*16 + wv)*16) + (k & 7)*2;
        *(unsigned short*)((char*)sm.rec.hL + hswz(byte)) = f2bf(h);
        if (g == 0) {
          out[(size_t)t*(BATCH*HID) + (size_t)brow*256 + s*64 + lane] = h;
          if (t == T_STEPS-1) {
            out[(size_t)T_STEPS*(BATCH*HID) + (size_t)brow*256 + s*64 + lane] = h;
            out[(size_t)T_STEPS*(BATCH*HID) + BATCH*HID + (size_t)brow*256 + s*64 + lane] = cn;
          }
        }
      }
      if ((t & 7) == 7 && tid == 0) add_rlx(consumed, 1);
      __syncthreads();   // hL(t) complete before next MFMA; z reads done
    }
  } else {
    // ================= xgemm producers (128x256 tiles, frag-linear LDS) =================
    int w0 = bid - NRWG;
    int wr = wv >> 2, wc = wv & 3;          // 2 x 4 wave grid, 64x64 per wave
    int rA = tid >> 2, kA = (tid & 3) * 8;  // A staging: 128 rows x 32 k
    int rB = tid >> 1, kB = (tid & 1) * 16; // B staging: 256 cols x 32 k

    for (int gt = w0; gt < NCHUNK * TPC; gt += NWWG) {
      int c  = gt >> 6;
      int tl = gt & 63;
      int tm = tl >> 2, tn = tl & 3;

      int need = NRWG * (c - RING + 1);
      if (need > 0) {
        if (tid == 0) { while (ld_rlx(consumed) < need) __builtin_amdgcn_s_sleep(8); }
        __syncthreads();
      }

      const float* Xb = X + ((size_t)c*(CHUNK*256) + (size_t)tm*128) * 512;
      float* slotp = ring + (size_t)(c & (RING-1)) * SLOT_F;

      f32x4 acc[4][4];
#pragma unroll
      for (int mi = 0; mi < 4; ++mi)
#pragma unroll
        for (int ni = 0; ni < 4; ++ni) acc[mi][ni] = (f32x4){0.f,0.f,0.f,0.f};

      int slotA = (rA >> 4)*1024 + ((tid & 3)*16 + (rA & 15))*16;
      int baseB = (rB >> 4)*1024;
      int kO = kB >> 3;
      int slotB0 = baseB + ((kO    )*16 + (rB & 15))*16;
      int slotB1 = baseB + ((kO + 1)*16 + (rB & 15))*16;

      for (int kb = 0; kb < 512; kb += 32) {
        const float* ap = Xb + (size_t)rA*512 + kb + kA;
        f32x4 v0 = *(const f32x4*)ap;
        f32x4 v1 = *(const f32x4*)(ap + 4);
        unsigned short t8[8];
        t8[0]=f2bf(v0[0]); t8[1]=f2bf(v0[1]); t8[2]=f2bf(v0[2]); t8[3]=f2bf(v0[3]);
        t8[4]=f2bf(v1[0]); t8[5]=f2bf(v1[1]); t8[6]=f2bf(v1[2]); t8[7]=f2bf(v1[3]);
        *(short8*)((char*)sm.gem.aL + slotA) = *(short8*)t8;
        const unsigned short* bp = Wfull + (size_t)(tn*256 + rB)*768 + kb + kB;
        *(short8*)((char*)sm.gem.bL + slotB0) = *(const short8*)bp;
        *(short8*)((char*)sm.gem.bL + slotB1) = *(const short8*)(bp + 8);
        __syncthreads();

        short8 afr[4], bfr4[4];
#pragma unroll
        for (int mi = 0; mi < 4; ++mi)
          afr[mi]  = *(const short8*)((const char*)sm.gem.aL + (wr*4 + mi)*1024 + lane*16);
#pragma unroll
        for (int ni = 0; ni < 4; ++ni)
          bfr4[ni] = *(const short8*)((const char*)sm.gem.bL + (wc*4 + ni)*1024 + lane*16);
#pragma unroll
        for (int mi = 0; mi < 4; ++mi)
#pragma unroll
          for (int ni = 0; ni < 4; ++ni)
            acc[mi][ni] = __builtin_amdgcn_mfma_f32_16x16x32_bf16(afr[mi], bfr4[ni], acc[mi][ni], 0, 0, 0);
        __syncthreads();
      }

#pragma unroll
      for (int mi = 0; mi < 4; ++mi) {
#pragma unroll
        for (int ni = 0; ni < 4; ++ni) {
          int col = tn*256 + wc*64 + ni*16 + l15;
          float cv = cvec[col];
#pragma unroll
          for (int reg = 0; reg < 4; ++reg) {
            int row = tm*128 + wr*64 + mi*16 + lk*4 + reg;
            stg_coh(&slotp[(size_t)row*1024 + col], acc[mi][ni][reg] + cv);
          }
        }
      }
      VMCNT0();
      __syncthreads();                       // all waves' stores at LLC
      if (tid == 0) add_rlx(&done[c], 1);
    }
  }
}

// ---------------- host ----------------
extern "C" void kernel_launch(void* const* d_in, const int* in_sizes, int n_in,
                              void* d_out, int out_size, void* d_ws, size_t ws_size,
                              hipStream_t stream) {
  const float* x   = (const float*)d_in[0];
  const float* Wf  = (const float*)d_in[1];
  const float* bf_ = (const float*)d_in[2];
  const float* thf = (const float*)d_in[3];
  const float* Wi  = (const float*)d_in[4];
  const float* bi_ = (const float*)d_in[5];
  const float* thi = (const float*)d_in[6];
  const float* Wg  = (const float*)d_in[7];
  const float* bg_ = (const float*)d_in[8];
  const float* thg = (const float*)d_in[9];
  const float* Wo  = (const float*)d_in[10];
  const float* bo_ = (const float*)d_in[11];
  const float* tho = (const float*)d_in[12];
  float* out = (float*)d_out;

  char* ws = (char*)d_ws;
  unsigned short* Wfull = (unsigned short*)ws;            // 1.5 MB
  float* cvec  = (float*)(ws + 1572864);                  // 4 KB
  int*   flags = (int*)(ws + 1576960);                    // 512 ints
  float* pk    = (float*)(ws + 2097152);                  // 4 MB packets
  float* ring  = (float*)(ws + 8388608);                  // RING x 8 MB = 32 MB

  prep_kernel<<<1024, 256, 0, stream>>>(Wf, Wi, Wg, Wo, bf_, bi_, bg_, bo_,
                                        thf, thi, thg, tho, Wfull, cvec, flags, pk);
  persist_kernel<<<NWG, 512, 0, stream>>>(x, Wfull, cvec, ring, pk,
                                          flags, flags + 128, out);
}